// Round 5
// baseline (406.701 us; speedup 1.0000x reference)
//
#include <hip/hip_runtime.h>

#define NN 50000     // nodes
#define NE 800000    // edges
#define NG 1024      // graphs
#define NP 16384     // pairs
#define NCL 16       // cell lines
#define INCH 64
#define EMB 128
#define HID 256

#define CDIV(a,b) (((a)+(b)-1)/(b))
#define SCAN_BLOCKS CDIV(NN,256)   // 196

// ---------------- small utils ----------------
__global__ __launch_bounds__(256) void k_zeroi(int* p, int n) {
    int i = blockIdx.x * 256 + threadIdx.x;
    if (i < n) p[i] = 0;
}

__global__ __launch_bounds__(256) void k_deg(const int* __restrict__ col, int* __restrict__ deg) {
    int e = blockIdx.x * 256 + threadIdx.x;
    if (e < NE) atomicAdd(&deg[col[e]], 1);
}

// ---------------- exclusive scan of deg -> off (+ dinv fused) ----------------
__device__ __forceinline__ int block_excl_scan_256(int v, int t, int* incl_out) {
    int lane = t & 63, w = t >> 6;
    int s = v;
#pragma unroll
    for (int d = 1; d < 64; d <<= 1) {
        int u = __shfl_up(s, d, 64);
        if (lane >= d) s += u;
    }
    __shared__ int wsum[4];
    if (lane == 63) wsum[w] = s;
    __syncthreads();
    int add = 0;
    for (int k = 0; k < w; ++k) add += wsum[k];
    int incl = s + add;
    *incl_out = incl;
    return incl - v;
}

__global__ __launch_bounds__(256) void k_scan1(const int* __restrict__ deg,
                                               int* __restrict__ off,
                                               int* __restrict__ bsums,
                                               float* __restrict__ dinv) {
    int b = blockIdx.x, t = threadIdx.x;
    int i = b * 256 + t;
    int v = (i < NN) ? deg[i] : 0;
    int incl;
    int excl = block_excl_scan_256(v, t, &incl);
    if (i < NN) {
        off[i] = excl;
        dinv[i] = rsqrtf((float)(v + 1));   // +1 self-loop
    }
    if (t == 255) bsums[b] = incl;
}

__global__ __launch_bounds__(256) void k_scan2(int* __restrict__ bsums) {
    int t = threadIdx.x;
    int v = (t < SCAN_BLOCKS) ? bsums[t] : 0;
    int incl;
    int excl = block_excl_scan_256(v, t, &incl);
    __syncthreads();
    if (t < SCAN_BLOCKS) bsums[t] = excl;
}

__global__ __launch_bounds__(256) void k_scan3(int* __restrict__ off,
                                               const int* __restrict__ bsums) {
    int b = blockIdx.x, t = threadIdx.x;
    int i = b * 256 + t;
    if (i < NN) off[i] += bsums[b];
}

// ---------------- CSR fill ----------------
__global__ __launch_bounds__(256) void k_fill(const int* __restrict__ rows,
                                              const int* __restrict__ cols,
                                              int* __restrict__ off,
                                              int* __restrict__ srows) {
    int e = blockIdx.x * 256 + threadIdx.x;
    if (e >= NE) return;
    int c = cols[e];
    int pos = atomicAdd(&off[c], 1);
    srows[pos] = rows[e];
}

// ---------------- transpose x -> slice-blocked [s][node][16f] ----------------
__global__ __launch_bounds__(256) void k_xpose(const float* __restrict__ x,
                                               float* __restrict__ xt) {
    int i = blockIdx.x * 256 + threadIdx.x;    // over NN*16 float4s
    if (i >= NN * 16) return;
    int node = i >> 4, f4 = i & 15;
    float4 v = ((const float4*)x)[i];
    ((float4*)xt)[(((f4 >> 2) * NN + node) << 2) + (f4 & 3)] = v;
}

// ---------------- XCD-affine sliced gather ----------------
// Input/output slice-blocked [NSL][node][16f]. Block b -> slice b&(NSL-1) so
// round-robin dispatch pins each slice's 3.2MB working set to one XCD's L2.
// Wave = 1 node: 16 edge slots x 4 feature lanes (float4).
// DST[c] = dinv[c]*(sum_e dinv[r]*SRC[r] + dinv[c]*SRC[c])
template<int NSL>
__global__ __launch_bounds__(256) void k_gath(const int* __restrict__ off,
                                              const int* __restrict__ srows,
                                              const float* __restrict__ dinv,
                                              const float* __restrict__ SRC,
                                              float* __restrict__ DST) {
    int b = blockIdx.x;
    int s = b & (NSL - 1);
    int node = (b / NSL) * 4 + (threadIdx.x >> 6);
    if (node >= NN) return;
    int lane = threadIdx.x & 63;
    int slot = lane >> 2, q = lane & 3;
    int beg = node ? off[node - 1] : 0;
    int end = off[node];
    float di = dinv[node];
    const float4* S4 = (const float4*)SRC + (size_t)s * NN * 4;

    float4 acc = make_float4(0.f, 0.f, 0.f, 0.f);
    if (slot == 0) {
        float4 v = S4[node * 4 + q];
        acc = make_float4(di * v.x, di * v.y, di * v.z, di * v.w);
    }
    for (int e0 = beg; e0 < end; e0 += 16) {
        int e = e0 + slot;
        if (e < end) {
            int r = __builtin_nontemporal_load(&srows[e]);
            float w = dinv[r];
            float4 v = S4[r * 4 + q];
            acc.x = fmaf(w, v.x, acc.x);
            acc.y = fmaf(w, v.y, acc.y);
            acc.z = fmaf(w, v.z, acc.z);
            acc.w = fmaf(w, v.w, acc.w);
        }
    }
    // reduce over the 16 edge slots (xor on lane bits 2..5)
#pragma unroll
    for (int d = 4; d < 64; d <<= 1) {
        acc.x += __shfl_xor(acc.x, d, 64);
        acc.y += __shfl_xor(acc.y, d, 64);
        acc.z += __shfl_xor(acc.z, d, 64);
        acc.w += __shfl_xor(acc.w, d, 64);
    }
    if (slot == 0) {
        float4 o = make_float4(di * acc.x, di * acc.y, di * acc.z, di * acc.w);
        ((float4*)DST)[((size_t)s * NN + node) * 4 + q] = o;
    }
}

// ---------------- GEMM: Y[M,128] = X[M,K] @ W[K,128] (+bias,relu) ----------------
// 256 thr: block = 32 rows x 128 cols; thread = 4r x 4c; KC=32.
// BIN: X is slice-blocked [K/16][M][16f]; BOUT: Y written slice-blocked.
template<int K, bool BIN, bool BOUT, bool EPI>
__global__ __launch_bounds__(256) void gemm32(const float* __restrict__ X,
                                              const float* __restrict__ W,
                                              const float* __restrict__ bias,
                                              float* __restrict__ Y, int M) {
    __shared__ float Xt[32][36];
    __shared__ float Wsh[32][128];
    const int t  = threadIdx.x;
    const int tr = t >> 5;
    const int tc = t & 31;
    const int row0 = blockIdx.x * 32;
    const int rr = t >> 3, kq = t & 7;

    float acc[4][4];
#pragma unroll
    for (int i = 0; i < 4; ++i)
#pragma unroll
        for (int j = 0; j < 4; ++j) acc[i][j] = 0.f;

    const float4* X4 = (const float4*)X;
    const float4* W4 = (const float4*)W;
    float4* Ws4 = (float4*)&Wsh[0][0];

    for (int k0 = 0; k0 < K; k0 += 32) {
        __syncthreads();
        int gr = row0 + rr;
        float4 xv = make_float4(0.f, 0.f, 0.f, 0.f);
        if (gr < M) {
            int F = (k0 >> 2) + kq;      // global float4 feature index
            xv = BIN ? X4[(((F >> 2) * M + gr) << 2) + (F & 3)]
                     : X4[gr * (K >> 2) + F];
        }
        Xt[4 * kq + 0][rr] = xv.x;
        Xt[4 * kq + 1][rr] = xv.y;
        Xt[4 * kq + 2][rr] = xv.z;
        Xt[4 * kq + 3][rr] = xv.w;
#pragma unroll
        for (int i = t; i < 32 * 32; i += 256)
            Ws4[i] = W4[(k0 + (i >> 5)) * 32 + (i & 31)];
        __syncthreads();
#pragma unroll 4
        for (int k = 0; k < 32; ++k) {
            float4 xf = *reinterpret_cast<const float4*>(&Xt[k][4 * tr]);
            float4 wf = *reinterpret_cast<const float4*>(&Wsh[k][4 * tc]);
            float xs[4] = {xf.x, xf.y, xf.z, xf.w};
            float ws[4] = {wf.x, wf.y, wf.z, wf.w};
#pragma unroll
            for (int i = 0; i < 4; ++i)
#pragma unroll
                for (int j = 0; j < 4; ++j)
                    acc[i][j] = fmaf(xs[i], ws[j], acc[i][j]);
        }
    }
    float4 b = make_float4(0.f, 0.f, 0.f, 0.f);
    if (EPI) b = ((const float4*)bias)[tc];
    float4* Y4 = (float4*)Y;
#pragma unroll
    for (int i = 0; i < 4; ++i) {
        int gr = row0 + 4 * tr + i;
        if (gr < M) {
            float4 o = make_float4(acc[i][0] + b.x, acc[i][1] + b.y,
                                   acc[i][2] + b.z, acc[i][3] + b.w);
            if (EPI) {
                o.x = o.x > 0.f ? o.x : 0.f;
                o.y = o.y > 0.f ? o.y : 0.f;
                o.z = o.z > 0.f ? o.z : 0.f;
                o.w = o.w > 0.f ? o.w : 0.f;
            }
            if (BOUT) Y4[(((tc >> 2) * M + gr) << 2) + (tc & 3)] = o;
            else      Y4[gr * 32 + tc] = o;
        }
    }
}

// ---------------- mean pool (gstart search fused) ----------------
__global__ __launch_bounds__(128) void k_pool2(const float* __restrict__ H,
                                               const int* __restrict__ batch,
                                               float* __restrict__ gsum) {
    int g = blockIdx.x;
    __shared__ int se[2];
    if (threadIdx.x < 2) {
        int tgt = g + threadIdx.x;
        int lo = 0, hi = NN;
        while (lo < hi) {
            int m = (lo + hi) >> 1;
            if (batch[m] < tgt) lo = m + 1; else hi = m;
        }
        se[threadIdx.x] = lo;
    }
    __syncthreads();
    int s = se[0], e = se[1];
    int j = threadIdx.x;
    float acc = 0.f;
    for (int i = s; i < e; ++i) acc += H[(long long)i * 128 + j];
    float c = (float)(e - s);
    gsum[g * 128 + j] = acc / fmaxf(c, 1.f);
}

// ---------------- batched GEMM: AB[z][g][t] = GE @ W1-half ----------------
__global__ __launch_bounds__(256) void gemm_bat(const float* __restrict__ GE,
                                                const float* __restrict__ W1,
                                                float* __restrict__ AB) {
    __shared__ float Xt[32][36];
    __shared__ float Wsh[32][128];
    const int t  = threadIdx.x;
    const int tr = t >> 5, tc = t & 31;
    const int row0 = blockIdx.x * 32;
    const int y = blockIdx.y;
    const int z = blockIdx.z;
    const int rr = t >> 3, kq = t & 7;

    const float* Wbase = W1 + (z >> 1) * (HID * HID) + (z & 1) * (128 * HID) + y * 128;

    float acc[4][4];
#pragma unroll
    for (int i = 0; i < 4; ++i)
#pragma unroll
        for (int j = 0; j < 4; ++j) acc[i][j] = 0.f;

    const float4* X4 = (const float4*)GE;
    float4* Ws4 = (float4*)&Wsh[0][0];

    for (int k0 = 0; k0 < 128; k0 += 32) {
        __syncthreads();
        float4 xv = X4[((row0 + rr) * 128 + k0 + 4 * kq) >> 2];
        Xt[4 * kq + 0][rr] = xv.x;
        Xt[4 * kq + 1][rr] = xv.y;
        Xt[4 * kq + 2][rr] = xv.z;
        Xt[4 * kq + 3][rr] = xv.w;
        const float4* Wc4 = (const float4*)(Wbase + k0 * HID);
#pragma unroll
        for (int i = t; i < 32 * 32; i += 256)
            Ws4[i] = Wc4[(i >> 5) * 64 + (i & 31)];
        __syncthreads();
#pragma unroll 4
        for (int k = 0; k < 32; ++k) {
            float4 xf = *reinterpret_cast<const float4*>(&Xt[k][4 * tr]);
            float4 wf = *reinterpret_cast<const float4*>(&Wsh[k][4 * tc]);
            float xs[4] = {xf.x, xf.y, xf.z, xf.w};
            float ws[4] = {wf.x, wf.y, wf.z, wf.w};
#pragma unroll
            for (int i = 0; i < 4; ++i)
#pragma unroll
                for (int j = 0; j < 4; ++j)
                    acc[i][j] = fmaf(xs[i], ws[j], acc[i][j]);
        }
    }
    float4* O4 = (float4*)AB;
#pragma unroll
    for (int i = 0; i < 4; ++i) {
        int g = row0 + 4 * tr + i;
        O4[((z * NG + g) * HID + y * 128) / 4 + tc] =
            make_float4(acc[i][0], acc[i][1], acc[i][2], acc[i][3]);
    }
}

// ---------------- pair epilogue ----------------
__global__ __launch_bounds__(256) void k_pair(const float* __restrict__ AB,
                                              const int* __restrict__ ddb,
                                              const int* __restrict__ ecl,
                                              const float* __restrict__ B1,
                                              const float* __restrict__ W2,
                                              const float* __restrict__ B2,
                                              float* __restrict__ out) {
    int p = blockIdx.x * 4 + (threadIdx.x >> 6);
    int lane = threadIdx.x & 63;
    int c = ecl[p];
    int a = ddb[p];
    int b = ddb[NP + p];
    const float4* rA = (const float4*)&AB[((c * 2 + 0) * NG + a) * HID];
    const float4* rB = (const float4*)&AB[((c * 2 + 1) * NG + b) * HID];
    const float4* b1 = (const float4*)&B1[c * HID];
    const float4* w2 = (const float4*)&W2[c * HID];
    float4 va = rA[lane], vb = rB[lane], v1 = b1[lane], v2 = w2[lane];
    float hx = va.x + vb.x + v1.x;
    float hy = va.y + vb.y + v1.y;
    float hz = va.z + vb.z + v1.z;
    float hw = va.w + vb.w + v1.w;
    float s = 0.f;
    s = fmaf(hx > 0.f ? hx : 0.f, v2.x, s);
    s = fmaf(hy > 0.f ? hy : 0.f, v2.y, s);
    s = fmaf(hz > 0.f ? hz : 0.f, v2.z, s);
    s = fmaf(hw > 0.f ? hw : 0.f, v2.w, s);
    for (int o = 32; o; o >>= 1) s += __shfl_down(s, o, 64);
    if (lane == 0) out[p] = s + B2[c];
}

// ---------------- launch ----------------
extern "C" void kernel_launch(void* const* d_in, const int* in_sizes, int n_in,
                              void* d_out, int out_size, void* d_ws, size_t ws_size,
                              hipStream_t stream) {
    const float* x    = (const float*)d_in[0];
    const float* c1w  = (const float*)d_in[1];
    const float* c1b  = (const float*)d_in[2];
    const float* c2w  = (const float*)d_in[3];
    const float* c2b  = (const float*)d_in[4];
    const float* rw1  = (const float*)d_in[5];
    const float* rb1  = (const float*)d_in[6];
    const float* rw2  = (const float*)d_in[7];
    const float* rb2  = (const float*)d_in[8];
    const int*   eidx = (const int*)d_in[9];    // [2, NE]: rows then cols
    const int*   batch= (const int*)d_in[10];
    const int*   ddb  = (const int*)d_in[11];   // [2, NP]
    const int*   ecl  = (const int*)d_in[12];
    float* out = (float*)d_out;

    // ---- workspace layout (floats) ----
    // off(50048) | srows(NE) | dinv(50048) | bufA(NN*128) | bufB(NN*128)
    // transient in bufA pre-gather1: degi, bsums
    // transient in bufB pre-gemm1: xt (NN*64 = 3.2M floats, dead once gather1 done)
    // transient in srows post-pool: gsum(NG*EMB)
    // transient over bufA(+into bufB) post-pool: AB (32*NG*HID)
    int*   off   = (int*)d_ws;
    int*   srows = off + 50048;
    float* dinv  = (float*)(srows + NE);
    float* bufA  = dinv + 50048;
    float* bufB  = bufA + NN * EMB;

    int*   degi  = (int*)bufA;
    int*   bsums = degi + 50048;
    float* xt    = bufB;               // alive only until gather1
    float* gsum  = (float*)srows;      // alive only after pool
    float* AB    = bufA;               // alive only after pool

    const int* erow = eidx;
    const int* ecol = eidx + NE;

    // ---- CSR build ----
    k_zeroi<<<CDIV(NN,256),256,0,stream>>>(degi, NN);
    k_deg<<<CDIV(NE,256),256,0,stream>>>(ecol, degi);
    k_scan1<<<SCAN_BLOCKS,256,0,stream>>>(degi, off, bsums, dinv);
    k_scan2<<<1,256,0,stream>>>(bsums);
    k_scan3<<<SCAN_BLOCKS,256,0,stream>>>(off, bsums);
    k_fill<<<CDIV(NE,256),256,0,stream>>>(erow, ecol, off, srows);

    // ---- transpose x into slice-blocked layout (4 slices of 16f) ----
    k_xpose<<<CDIV(NN*16,256),256,0,stream>>>(x, xt);

    // ---- layer 1: aggX = A_hat @ x (sliced, XCD-affine) ; H1 = relu(aggX@W1+b1) blocked ----
    k_gath<4><<<4*CDIV(NN,4),256,0,stream>>>(off, srows, dinv, xt, bufA);
    gemm32<INCH,true,true,true><<<CDIV(NN,32),256,0,stream>>>(bufA, c1w, c1b, bufB, NN);

    // ---- layer 2: aggH = A_hat @ H1 (sliced) ; H2 = relu(aggH@W2+b2) row-major ----
    k_gath<8><<<8*CDIV(NN,4),256,0,stream>>>(off, srows, dinv, bufB, bufA);
    gemm32<EMB,true,false,true><<<CDIV(NN,32),256,0,stream>>>(bufA, c2w, c2b, bufB, NN);

    // ---- mean pool over sorted batch (srows/off/dinv dead; gsum aliases srows) ----
    k_pool2<<<NG,128,0,stream>>>(bufB, batch, gsum);

    // ---- regressor: precompute GE @ W1 halves for all 16 lines ----
    dim3 bgrid(NG/32, 2, 2*NCL);
    gemm_bat<<<bgrid,256,0,stream>>>(gsum, rw1, AB);
    k_pair<<<NP/4,256,0,stream>>>(AB, ddb, ecl, rb1, rw2, rb2, out);
}

// Round 6
// 297.406 us; speedup vs baseline: 1.3675x; 1.3675x over previous
//
#include <hip/hip_runtime.h>

#define NN 50000     // nodes
#define NE 800000    // edges
#define NG 1024      // graphs
#define NP 16384     // pairs
#define NCL 16       // cell lines
#define INCH 64
#define EMB 128
#define HID 256

#define CDIV(a,b) (((a)+(b)-1)/(b))
#define SCAN_BLOCKS CDIV(NN,256)   // 196

// ---------------- small utils ----------------
__global__ __launch_bounds__(256) void k_zeroi(int* p, int n) {
    int i = blockIdx.x * 256 + threadIdx.x;
    if (i < n) p[i] = 0;
}

__global__ __launch_bounds__(256) void k_deg(const int* __restrict__ col, int* __restrict__ deg) {
    int e = blockIdx.x * 256 + threadIdx.x;
    if (e < NE) atomicAdd(&deg[col[e]], 1);
}

// ---------------- exclusive scan of deg -> off (+ dinv fused) ----------------
__device__ __forceinline__ int block_excl_scan_256(int v, int t, int* incl_out) {
    int lane = t & 63, w = t >> 6;
    int s = v;
#pragma unroll
    for (int d = 1; d < 64; d <<= 1) {
        int u = __shfl_up(s, d, 64);
        if (lane >= d) s += u;
    }
    __shared__ int wsum[4];
    if (lane == 63) wsum[w] = s;
    __syncthreads();
    int add = 0;
    for (int k = 0; k < w; ++k) add += wsum[k];
    int incl = s + add;
    *incl_out = incl;
    return incl - v;
}

__global__ __launch_bounds__(256) void k_scan1(const int* __restrict__ deg,
                                               int* __restrict__ off,
                                               int* __restrict__ bsums,
                                               float* __restrict__ dinv) {
    int b = blockIdx.x, t = threadIdx.x;
    int i = b * 256 + t;
    int v = (i < NN) ? deg[i] : 0;
    int incl;
    int excl = block_excl_scan_256(v, t, &incl);
    if (i < NN) {
        off[i] = excl;
        dinv[i] = rsqrtf((float)(v + 1));   // +1 self-loop
    }
    if (t == 255) bsums[b] = incl;
}

__global__ __launch_bounds__(256) void k_scan2(int* __restrict__ bsums) {
    int t = threadIdx.x;
    int v = (t < SCAN_BLOCKS) ? bsums[t] : 0;
    int incl;
    int excl = block_excl_scan_256(v, t, &incl);
    __syncthreads();
    if (t < SCAN_BLOCKS) bsums[t] = excl;
}

__global__ __launch_bounds__(256) void k_scan3(int* __restrict__ off,
                                               const int* __restrict__ bsums) {
    int b = blockIdx.x, t = threadIdx.x;
    int i = b * 256 + t;
    if (i < NN) off[i] += bsums[b];
}

// ---------------- CSR fill ----------------
__global__ __launch_bounds__(256) void k_fill(const int* __restrict__ rows,
                                              const int* __restrict__ cols,
                                              int* __restrict__ off,
                                              int* __restrict__ srows) {
    int e = blockIdx.x * 256 + threadIdx.x;
    if (e >= NE) return;
    int c = cols[e];
    int pos = atomicAdd(&off[c], 1);
    srows[pos] = rows[e];
}

// ---------------- pre-scale x by dinv[row] ----------------
__global__ __launch_bounds__(256) void k_scalex(const float* __restrict__ x,
                                                const float* __restrict__ dinv,
                                                float* __restrict__ xs) {
    int i = blockIdx.x * 256 + threadIdx.x;    // over NN*16 float4s
    if (i >= NN * 16) return;
    float d = dinv[i >> 4];
    float4 v = ((const float4*)x)[i];
    ((float4*)xs)[i] = make_float4(d * v.x, d * v.y, d * v.z, d * v.w);
}

// ---------------- gather on pre-scaled rows ----------------
// SRC' already scaled by dinv[row]; DST[c] = dinv[c]*(sum_e SRC'[r] + SRC'[c]).
// Wave = 1 node; 8 edge slots x 8 feature lanes x PL float4s.
template<int FEAT>
__global__ __launch_bounds__(256) void k_gath(const int* __restrict__ off,
                                              const int* __restrict__ srows,
                                              const float* __restrict__ dinv,
                                              const float* __restrict__ SRC,
                                              float* __restrict__ DST) {
    constexpr int NV4 = FEAT / 4;   // float4s per row
    constexpr int PL  = NV4 / 8;    // float4s per lane (2 or 4)
    int node = blockIdx.x * 4 + (threadIdx.x >> 6);
    int lane = threadIdx.x & 63;
    int slot = lane >> 3, q = lane & 7;
    if (node >= NN) return;
    int beg = node ? off[node - 1] : 0;
    int end = off[node];
    float di = dinv[node];
    const float4* S4 = (const float4*)SRC;

    float4 acc[PL];
#pragma unroll
    for (int i = 0; i < PL; ++i) acc[i] = make_float4(0.f, 0.f, 0.f, 0.f);
    if (slot == 0) {
#pragma unroll
        for (int i = 0; i < PL; ++i) acc[i] = S4[node * NV4 + i * 8 + q];
    }
    for (int e = beg + slot; e < end; e += 8) {
        int r = srows[e];
#pragma unroll
        for (int i = 0; i < PL; ++i) {
            float4 v = S4[r * NV4 + i * 8 + q];
            acc[i].x += v.x; acc[i].y += v.y;
            acc[i].z += v.z; acc[i].w += v.w;
        }
    }
    // reduce over the 8 edge slots (xor lane bits 3,4,5)
#pragma unroll
    for (int d = 8; d < 64; d <<= 1) {
#pragma unroll
        for (int i = 0; i < PL; ++i) {
            acc[i].x += __shfl_xor(acc[i].x, d, 64);
            acc[i].y += __shfl_xor(acc[i].y, d, 64);
            acc[i].z += __shfl_xor(acc[i].z, d, 64);
            acc[i].w += __shfl_xor(acc[i].w, d, 64);
        }
    }
    if (lane < 8) {
        float4* D4 = (float4*)DST;
#pragma unroll
        for (int i = 0; i < PL; ++i) {
            float4 o = make_float4(di * acc[i].x, di * acc[i].y,
                                   di * acc[i].z, di * acc[i].w);
            D4[node * NV4 + i * 8 + lane] = o;
        }
    }
}

// ---------------- GEMM: Y[M,128] = X[M,K] @ W[K,128] (+bias,relu[,rowscale]) ----------------
// 256 thr: block = 32 rows x 128 cols; thread = 4r x 4c; KC=32.
template<int K, bool EPI, bool RS>
__global__ __launch_bounds__(256) void gemm32(const float* __restrict__ X,
                                              const float* __restrict__ W,
                                              const float* __restrict__ bias,
                                              const float* __restrict__ rs,
                                              float* __restrict__ Y, int M) {
    __shared__ float Xt[32][36];
    __shared__ float Wsh[32][128];
    const int t  = threadIdx.x;
    const int tr = t >> 5;
    const int tc = t & 31;
    const int row0 = blockIdx.x * 32;
    const int rr = t >> 3, kq = t & 7;

    float acc[4][4];
#pragma unroll
    for (int i = 0; i < 4; ++i)
#pragma unroll
        for (int j = 0; j < 4; ++j) acc[i][j] = 0.f;

    const float4* X4 = (const float4*)X;
    const float4* W4 = (const float4*)W;
    float4* Ws4 = (float4*)&Wsh[0][0];

    for (int k0 = 0; k0 < K; k0 += 32) {
        __syncthreads();
        int gr = row0 + rr;
        float4 xv = (gr < M) ? X4[gr * (K >> 2) + (k0 >> 2) + kq]
                             : make_float4(0.f, 0.f, 0.f, 0.f);
        Xt[4 * kq + 0][rr] = xv.x;
        Xt[4 * kq + 1][rr] = xv.y;
        Xt[4 * kq + 2][rr] = xv.z;
        Xt[4 * kq + 3][rr] = xv.w;
#pragma unroll
        for (int i = t; i < 32 * 32; i += 256)
            Ws4[i] = W4[(k0 + (i >> 5)) * 32 + (i & 31)];
        __syncthreads();
#pragma unroll 4
        for (int k = 0; k < 32; ++k) {
            float4 xf = *reinterpret_cast<const float4*>(&Xt[k][4 * tr]);
            float4 wf = *reinterpret_cast<const float4*>(&Wsh[k][4 * tc]);
            float xs[4] = {xf.x, xf.y, xf.z, xf.w};
            float ws[4] = {wf.x, wf.y, wf.z, wf.w};
#pragma unroll
            for (int i = 0; i < 4; ++i)
#pragma unroll
                for (int j = 0; j < 4; ++j)
                    acc[i][j] = fmaf(xs[i], ws[j], acc[i][j]);
        }
    }
    float4 b = make_float4(0.f, 0.f, 0.f, 0.f);
    if (EPI) b = ((const float4*)bias)[tc];
    float4* Y4 = (float4*)Y;
#pragma unroll
    for (int i = 0; i < 4; ++i) {
        int gr = row0 + 4 * tr + i;
        if (gr < M) {
            float4 o = make_float4(acc[i][0] + b.x, acc[i][1] + b.y,
                                   acc[i][2] + b.z, acc[i][3] + b.w);
            if (EPI) {
                o.x = o.x > 0.f ? o.x : 0.f;
                o.y = o.y > 0.f ? o.y : 0.f;
                o.z = o.z > 0.f ? o.z : 0.f;
                o.w = o.w > 0.f ? o.w : 0.f;
            }
            if (RS) {
                float d = rs[gr];
                o.x *= d; o.y *= d; o.z *= d; o.w *= d;
            }
            Y4[gr * 32 + tc] = o;
        }
    }
}

// ---------------- mean pool (gstart search fused) ----------------
__global__ __launch_bounds__(128) void k_pool2(const float* __restrict__ H,
                                               const int* __restrict__ batch,
                                               float* __restrict__ gsum) {
    int g = blockIdx.x;
    __shared__ int se[2];
    if (threadIdx.x < 2) {
        int tgt = g + threadIdx.x;
        int lo = 0, hi = NN;
        while (lo < hi) {
            int m = (lo + hi) >> 1;
            if (batch[m] < tgt) lo = m + 1; else hi = m;
        }
        se[threadIdx.x] = lo;
    }
    __syncthreads();
    int s = se[0], e = se[1];
    int j = threadIdx.x;
    float acc = 0.f;
    for (int i = s; i < e; ++i) acc += H[(long long)i * 128 + j];
    float c = (float)(e - s);
    gsum[g * 128 + j] = acc / fmaxf(c, 1.f);
}

// ---------------- batched GEMM: AB[z][g][t] = GE @ W1-half ----------------
__global__ __launch_bounds__(256) void gemm_bat(const float* __restrict__ GE,
                                                const float* __restrict__ W1,
                                                float* __restrict__ AB) {
    __shared__ float Xt[32][36];
    __shared__ float Wsh[32][128];
    const int t  = threadIdx.x;
    const int tr = t >> 5, tc = t & 31;
    const int row0 = blockIdx.x * 32;
    const int y = blockIdx.y;
    const int z = blockIdx.z;
    const int rr = t >> 3, kq = t & 7;

    const float* Wbase = W1 + (z >> 1) * (HID * HID) + (z & 1) * (128 * HID) + y * 128;

    float acc[4][4];
#pragma unroll
    for (int i = 0; i < 4; ++i)
#pragma unroll
        for (int j = 0; j < 4; ++j) acc[i][j] = 0.f;

    const float4* X4 = (const float4*)GE;
    float4* Ws4 = (float4*)&Wsh[0][0];

    for (int k0 = 0; k0 < 128; k0 += 32) {
        __syncthreads();
        float4 xv = X4[((row0 + rr) * 128 + k0 + 4 * kq) >> 2];
        Xt[4 * kq + 0][rr] = xv.x;
        Xt[4 * kq + 1][rr] = xv.y;
        Xt[4 * kq + 2][rr] = xv.z;
        Xt[4 * kq + 3][rr] = xv.w;
        const float4* Wc4 = (const float4*)(Wbase + k0 * HID);
#pragma unroll
        for (int i = t; i < 32 * 32; i += 256)
            Ws4[i] = Wc4[(i >> 5) * 64 + (i & 31)];
        __syncthreads();
#pragma unroll 4
        for (int k = 0; k < 32; ++k) {
            float4 xf = *reinterpret_cast<const float4*>(&Xt[k][4 * tr]);
            float4 wf = *reinterpret_cast<const float4*>(&Wsh[k][4 * tc]);
            float xs[4] = {xf.x, xf.y, xf.z, xf.w};
            float ws[4] = {wf.x, wf.y, wf.z, wf.w};
#pragma unroll
            for (int i = 0; i < 4; ++i)
#pragma unroll
                for (int j = 0; j < 4; ++j)
                    acc[i][j] = fmaf(xs[i], ws[j], acc[i][j]);
        }
    }
    float4* O4 = (float4*)AB;
#pragma unroll
    for (int i = 0; i < 4; ++i) {
        int g = row0 + 4 * tr + i;
        O4[((z * NG + g) * HID + y * 128) / 4 + tc] =
            make_float4(acc[i][0], acc[i][1], acc[i][2], acc[i][3]);
    }
}

// ---------------- pair epilogue ----------------
__global__ __launch_bounds__(256) void k_pair(const float* __restrict__ AB,
                                              const int* __restrict__ ddb,
                                              const int* __restrict__ ecl,
                                              const float* __restrict__ B1,
                                              const float* __restrict__ W2,
                                              const float* __restrict__ B2,
                                              float* __restrict__ out) {
    int p = blockIdx.x * 4 + (threadIdx.x >> 6);
    int lane = threadIdx.x & 63;
    int c = ecl[p];
    int a = ddb[p];
    int b = ddb[NP + p];
    const float4* rA = (const float4*)&AB[((c * 2 + 0) * NG + a) * HID];
    const float4* rB = (const float4*)&AB[((c * 2 + 1) * NG + b) * HID];
    const float4* b1 = (const float4*)&B1[c * HID];
    const float4* w2 = (const float4*)&W2[c * HID];
    float4 va = rA[lane], vb = rB[lane], v1 = b1[lane], v2 = w2[lane];
    float hx = va.x + vb.x + v1.x;
    float hy = va.y + vb.y + v1.y;
    float hz = va.z + vb.z + v1.z;
    float hw = va.w + vb.w + v1.w;
    float s = 0.f;
    s = fmaf(hx > 0.f ? hx : 0.f, v2.x, s);
    s = fmaf(hy > 0.f ? hy : 0.f, v2.y, s);
    s = fmaf(hz > 0.f ? hz : 0.f, v2.z, s);
    s = fmaf(hw > 0.f ? hw : 0.f, v2.w, s);
    for (int o = 32; o; o >>= 1) s += __shfl_down(s, o, 64);
    if (lane == 0) out[p] = s + B2[c];
}

// ---------------- launch ----------------
extern "C" void kernel_launch(void* const* d_in, const int* in_sizes, int n_in,
                              void* d_out, int out_size, void* d_ws, size_t ws_size,
                              hipStream_t stream) {
    const float* x    = (const float*)d_in[0];
    const float* c1w  = (const float*)d_in[1];
    const float* c1b  = (const float*)d_in[2];
    const float* c2w  = (const float*)d_in[3];
    const float* c2b  = (const float*)d_in[4];
    const float* rw1  = (const float*)d_in[5];
    const float* rb1  = (const float*)d_in[6];
    const float* rw2  = (const float*)d_in[7];
    const float* rb2  = (const float*)d_in[8];
    const int*   eidx = (const int*)d_in[9];    // [2, NE]: rows then cols
    const int*   batch= (const int*)d_in[10];
    const int*   ddb  = (const int*)d_in[11];   // [2, NP]
    const int*   ecl  = (const int*)d_in[12];
    float* out = (float*)d_out;

    // ---- workspace layout (floats) ----
    // off(50048) | srows(NE) | dinv(50048) | bufA(NN*128) | bufB(NN*128)
    // transient in bufA pre-gather1: degi, bsums
    // transient in bufB pre-gemm1: xs (NN*64, dead once gather1 done)
    // transient in srows post-pool: gsum(NG*EMB)
    // transient over bufA(+into bufB) post-pool: AB (32*NG*HID)
    int*   off   = (int*)d_ws;
    int*   srows = off + 50048;
    float* dinv  = (float*)(srows + NE);
    float* bufA  = dinv + 50048;
    float* bufB  = bufA + NN * EMB;

    int*   degi  = (int*)bufA;
    int*   bsums = degi + 50048;
    float* xs    = bufB;               // alive only until gather1
    float* gsum  = (float*)srows;      // alive only after pool
    float* AB    = bufA;               // alive only after pool

    const int* erow = eidx;
    const int* ecol = eidx + NE;

    // ---- CSR build ----
    k_zeroi<<<CDIV(NN,256),256,0,stream>>>(degi, NN);
    k_deg<<<CDIV(NE,256),256,0,stream>>>(ecol, degi);
    k_scan1<<<SCAN_BLOCKS,256,0,stream>>>(degi, off, bsums, dinv);
    k_scan2<<<1,256,0,stream>>>(bsums);
    k_scan3<<<SCAN_BLOCKS,256,0,stream>>>(off, bsums);
    k_fill<<<CDIV(NE,256),256,0,stream>>>(erow, ecol, off, srows);

    // ---- layer 1: x' = dinv*x ; aggX = gather(x') ; H1' = dinv*relu(aggX@W1+b1) ----
    k_scalex<<<CDIV(NN*16,256),256,0,stream>>>(x, dinv, xs);
    k_gath<INCH><<<CDIV(NN,4),256,0,stream>>>(off, srows, dinv, xs, bufA);
    gemm32<INCH,true,true><<<CDIV(NN,32),256,0,stream>>>(bufA, c1w, c1b, dinv, bufB, NN);

    // ---- layer 2: aggH = gather(H1') ; H2 = relu(aggH@W2+b2) ----
    k_gath<EMB><<<CDIV(NN,4),256,0,stream>>>(off, srows, dinv, bufB, bufA);
    gemm32<EMB,true,false><<<CDIV(NN,32),256,0,stream>>>(bufA, c2w, c2b, nullptr, bufB, NN);

    // ---- mean pool over sorted batch (srows/off/dinv dead; gsum aliases srows) ----
    k_pool2<<<NG,128,0,stream>>>(bufB, batch, gsum);

    // ---- regressor: precompute GE @ W1 halves for all 16 lines ----
    dim3 bgrid(NG/32, 2, 2*NCL);
    gemm_bat<<<bgrid,256,0,stream>>>(gsum, rw1, AB);
    k_pair<<<NP/4,256,0,stream>>>(AB, ddb, ecl, rb1, rw2, rb2, out);
}

// Round 7
// 270.636 us; speedup vs baseline: 1.5028x; 1.0989x over previous
//
#include <hip/hip_runtime.h>
#include <hip/hip_fp16.h>

#define NN 50000     // nodes
#define NE 800000    // edges
#define NG 1024      // graphs
#define NP 16384     // pairs
#define NCL 16       // cell lines
#define INCH 64
#define EMB 128
#define HID 256

#define CDIV(a,b) (((a)+(b)-1)/(b))
#define SCAN_BLOCKS CDIV(NN,256)   // 196

// ---------------- small utils ----------------
__global__ __launch_bounds__(256) void k_zeroi(int* p, int n) {
    int i = blockIdx.x * 256 + threadIdx.x;
    if (i < n) p[i] = 0;
}

__global__ __launch_bounds__(256) void k_deg(const int* __restrict__ col, int* __restrict__ deg) {
    int e = blockIdx.x * 256 + threadIdx.x;
    if (e < NE) atomicAdd(&deg[col[e]], 1);
}

// ---------------- exclusive scan of deg -> off (+ dinv fused) ----------------
__device__ __forceinline__ int block_excl_scan_256(int v, int t, int* incl_out) {
    int lane = t & 63, w = t >> 6;
    int s = v;
#pragma unroll
    for (int d = 1; d < 64; d <<= 1) {
        int u = __shfl_up(s, d, 64);
        if (lane >= d) s += u;
    }
    __shared__ int wsum[4];
    if (lane == 63) wsum[w] = s;
    __syncthreads();
    int add = 0;
    for (int k = 0; k < w; ++k) add += wsum[k];
    int incl = s + add;
    *incl_out = incl;
    return incl - v;
}

__global__ __launch_bounds__(256) void k_scan1(const int* __restrict__ deg,
                                               int* __restrict__ off,
                                               int* __restrict__ bsums,
                                               float* __restrict__ dinv) {
    int b = blockIdx.x, t = threadIdx.x;
    int i = b * 256 + t;
    int v = (i < NN) ? deg[i] : 0;
    int incl;
    int excl = block_excl_scan_256(v, t, &incl);
    if (i < NN) {
        off[i] = excl;
        dinv[i] = rsqrtf((float)(v + 1));   // +1 self-loop
    }
    if (t == 255) bsums[b] = incl;
}

__global__ __launch_bounds__(256) void k_scan2(int* __restrict__ bsums) {
    int t = threadIdx.x;
    int v = (t < SCAN_BLOCKS) ? bsums[t] : 0;
    int incl;
    int excl = block_excl_scan_256(v, t, &incl);
    __syncthreads();
    if (t < SCAN_BLOCKS) bsums[t] = excl;
}

__global__ __launch_bounds__(256) void k_scan3(int* __restrict__ off,
                                               const int* __restrict__ bsums) {
    int b = blockIdx.x, t = threadIdx.x;
    int i = b * 256 + t;
    if (i < NN) off[i] += bsums[b];
}

// ---------------- CSR fill ----------------
__global__ __launch_bounds__(256) void k_fill(const int* __restrict__ rows,
                                              const int* __restrict__ cols,
                                              int* __restrict__ off,
                                              int* __restrict__ srows) {
    int e = blockIdx.x * 256 + threadIdx.x;
    if (e >= NE) return;
    int c = cols[e];
    int pos = atomicAdd(&off[c], 1);
    srows[pos] = rows[e];
}

// ---------------- pre-scale x by dinv[row] -> fp16 ----------------
__global__ __launch_bounds__(256) void k_scalex(const float* __restrict__ x,
                                                const float* __restrict__ dinv,
                                                __half* __restrict__ xs) {
    int i = blockIdx.x * 256 + threadIdx.x;    // over NN*16 float4s
    if (i >= NN * 16) return;
    float d = dinv[i >> 4];
    float4 v = ((const float4*)x)[i];
    __half2 h[2];
    h[0] = __floats2half2_rn(d * v.x, d * v.y);
    h[1] = __floats2half2_rn(d * v.z, d * v.w);
    ((float2*)xs)[i] = *(float2*)h;
}

// ---------------- gather on pre-scaled fp16 rows ----------------
// SRC' (fp16) already scaled by dinv[row]; DST[c] = dinv[c]*(sum_e SRC'[r] + SRC'[c]).
// Wave = 1 node; 8 edge slots x 8 feature lanes x PL 16B-chunks (8 halfs each).
template<int FEAT>
__global__ __launch_bounds__(256) void k_gath_h(const int* __restrict__ off,
                                                const int* __restrict__ srows,
                                                const float* __restrict__ dinv,
                                                const __half* __restrict__ SRC,
                                                float* __restrict__ DST) {
    constexpr int NC = FEAT / 8;    // 16B chunks per row
    constexpr int PL = NC / 8;      // chunks per lane (1 for 64, 2 for 128)
    int node = blockIdx.x * 4 + (threadIdx.x >> 6);
    int lane = threadIdx.x & 63;
    int slot = lane >> 3, q = lane & 7;
    if (node >= NN) return;
    int beg = node ? off[node - 1] : 0;
    int end = off[node];
    float di = dinv[node];
    const float4* S4 = (const float4*)SRC;   // 16B = 8 halfs

    float acc[PL][8];
#pragma unroll
    for (int i = 0; i < PL; ++i)
#pragma unroll
        for (int j = 0; j < 8; ++j) acc[i][j] = 0.f;

    if (slot == 0) {
#pragma unroll
        for (int i = 0; i < PL; ++i) {
            float4 raw = S4[node * NC + i * 8 + q];
            const __half2* h = (const __half2*)&raw;
#pragma unroll
            for (int j = 0; j < 4; ++j) {
                float2 f = __half22float2(h[j]);
                acc[i][2 * j + 0] = f.x;
                acc[i][2 * j + 1] = f.y;
            }
        }
    }
    for (int e = beg + slot; e < end; e += 8) {
        int r = srows[e];
#pragma unroll
        for (int i = 0; i < PL; ++i) {
            float4 raw = S4[r * NC + i * 8 + q];
            const __half2* h = (const __half2*)&raw;
#pragma unroll
            for (int j = 0; j < 4; ++j) {
                float2 f = __half22float2(h[j]);
                acc[i][2 * j + 0] += f.x;
                acc[i][2 * j + 1] += f.y;
            }
        }
    }
    // reduce over the 8 edge slots (xor lane bits 3,4,5)
#pragma unroll
    for (int d = 8; d < 64; d <<= 1)
#pragma unroll
        for (int i = 0; i < PL; ++i)
#pragma unroll
            for (int j = 0; j < 8; ++j)
                acc[i][j] += __shfl_xor(acc[i][j], d, 64);

    if (lane < 8) {
        float4* D4 = (float4*)DST;            // f32 output
        constexpr int NV4 = FEAT / 4;
#pragma unroll
        for (int i = 0; i < PL; ++i) {
            float4 o0 = make_float4(di * acc[i][0], di * acc[i][1],
                                    di * acc[i][2], di * acc[i][3]);
            float4 o1 = make_float4(di * acc[i][4], di * acc[i][5],
                                    di * acc[i][6], di * acc[i][7]);
            D4[node * NV4 + (i * 8 + lane) * 2 + 0] = o0;
            D4[node * NV4 + (i * 8 + lane) * 2 + 1] = o1;
        }
    }
}

// ---------------- GEMM: Y[M,128] = X[M,K] @ W[K,128] (+bias,relu[,rowscale][,half out]) ----------------
// 256 thr: block = 32 rows x 128 cols; thread = 4r x 4c; KC=32.
template<int K, bool EPI, bool RS, bool HOUT>
__global__ __launch_bounds__(256) void gemm32(const float* __restrict__ X,
                                              const float* __restrict__ W,
                                              const float* __restrict__ bias,
                                              const float* __restrict__ rs,
                                              float* __restrict__ Y, int M) {
    __shared__ float Xt[32][36];
    __shared__ float Wsh[32][128];
    const int t  = threadIdx.x;
    const int tr = t >> 5;
    const int tc = t & 31;
    const int row0 = blockIdx.x * 32;
    const int rr = t >> 3, kq = t & 7;

    float acc[4][4];
#pragma unroll
    for (int i = 0; i < 4; ++i)
#pragma unroll
        for (int j = 0; j < 4; ++j) acc[i][j] = 0.f;

    const float4* X4 = (const float4*)X;
    const float4* W4 = (const float4*)W;
    float4* Ws4 = (float4*)&Wsh[0][0];

    for (int k0 = 0; k0 < K; k0 += 32) {
        __syncthreads();
        int gr = row0 + rr;
        float4 xv = (gr < M) ? X4[gr * (K >> 2) + (k0 >> 2) + kq]
                             : make_float4(0.f, 0.f, 0.f, 0.f);
        Xt[4 * kq + 0][rr] = xv.x;
        Xt[4 * kq + 1][rr] = xv.y;
        Xt[4 * kq + 2][rr] = xv.z;
        Xt[4 * kq + 3][rr] = xv.w;
#pragma unroll
        for (int i = t; i < 32 * 32; i += 256)
            Ws4[i] = W4[(k0 + (i >> 5)) * 32 + (i & 31)];
        __syncthreads();
#pragma unroll 4
        for (int k = 0; k < 32; ++k) {
            float4 xf = *reinterpret_cast<const float4*>(&Xt[k][4 * tr]);
            float4 wf = *reinterpret_cast<const float4*>(&Wsh[k][4 * tc]);
            float xs[4] = {xf.x, xf.y, xf.z, xf.w};
            float ws[4] = {wf.x, wf.y, wf.z, wf.w};
#pragma unroll
            for (int i = 0; i < 4; ++i)
#pragma unroll
                for (int j = 0; j < 4; ++j)
                    acc[i][j] = fmaf(xs[i], ws[j], acc[i][j]);
        }
    }
    float4 b = make_float4(0.f, 0.f, 0.f, 0.f);
    if (EPI) b = ((const float4*)bias)[tc];
    float4* Y4 = (float4*)Y;
    __half*  Yh = (__half*)Y;
#pragma unroll
    for (int i = 0; i < 4; ++i) {
        int gr = row0 + 4 * tr + i;
        if (gr < M) {
            float4 o = make_float4(acc[i][0] + b.x, acc[i][1] + b.y,
                                   acc[i][2] + b.z, acc[i][3] + b.w);
            if (EPI) {
                o.x = o.x > 0.f ? o.x : 0.f;
                o.y = o.y > 0.f ? o.y : 0.f;
                o.z = o.z > 0.f ? o.z : 0.f;
                o.w = o.w > 0.f ? o.w : 0.f;
            }
            if (RS) {
                float d = rs[gr];
                o.x *= d; o.y *= d; o.z *= d; o.w *= d;
            }
            if (HOUT) {
                __half2 h[2];
                h[0] = __floats2half2_rn(o.x, o.y);
                h[1] = __floats2half2_rn(o.z, o.w);
                ((float2*)Yh)[gr * 32 + tc] = *(float2*)h;
            } else {
                Y4[gr * 32 + tc] = o;
            }
        }
    }
}

// ---------------- mean pool (gstart search fused) ----------------
__global__ __launch_bounds__(128) void k_pool2(const float* __restrict__ H,
                                               const int* __restrict__ batch,
                                               float* __restrict__ gsum) {
    int g = blockIdx.x;
    __shared__ int se[2];
    if (threadIdx.x < 2) {
        int tgt = g + threadIdx.x;
        int lo = 0, hi = NN;
        while (lo < hi) {
            int m = (lo + hi) >> 1;
            if (batch[m] < tgt) lo = m + 1; else hi = m;
        }
        se[threadIdx.x] = lo;
    }
    __syncthreads();
    int s = se[0], e = se[1];
    int j = threadIdx.x;
    float acc = 0.f;
    for (int i = s; i < e; ++i) acc += H[(long long)i * 128 + j];
    float c = (float)(e - s);
    gsum[g * 128 + j] = acc / fmaxf(c, 1.f);
}

// ---------------- batched GEMM: AB[z][g][t] = GE @ W1-half ----------------
__global__ __launch_bounds__(256) void gemm_bat(const float* __restrict__ GE,
                                                const float* __restrict__ W1,
                                                float* __restrict__ AB) {
    __shared__ float Xt[32][36];
    __shared__ float Wsh[32][128];
    const int t  = threadIdx.x;
    const int tr = t >> 5, tc = t & 31;
    const int row0 = blockIdx.x * 32;
    const int y = blockIdx.y;
    const int z = blockIdx.z;
    const int rr = t >> 3, kq = t & 7;

    const float* Wbase = W1 + (z >> 1) * (HID * HID) + (z & 1) * (128 * HID) + y * 128;

    float acc[4][4];
#pragma unroll
    for (int i = 0; i < 4; ++i)
#pragma unroll
        for (int j = 0; j < 4; ++j) acc[i][j] = 0.f;

    const float4* X4 = (const float4*)GE;
    float4* Ws4 = (float4*)&Wsh[0][0];

    for (int k0 = 0; k0 < 128; k0 += 32) {
        __syncthreads();
        float4 xv = X4[((row0 + rr) * 128 + k0 + 4 * kq) >> 2];
        Xt[4 * kq + 0][rr] = xv.x;
        Xt[4 * kq + 1][rr] = xv.y;
        Xt[4 * kq + 2][rr] = xv.z;
        Xt[4 * kq + 3][rr] = xv.w;
        const float4* Wc4 = (const float4*)(Wbase + k0 * HID);
#pragma unroll
        for (int i = t; i < 32 * 32; i += 256)
            Ws4[i] = Wc4[(i >> 5) * 64 + (i & 31)];
        __syncthreads();
#pragma unroll 4
        for (int k = 0; k < 32; ++k) {
            float4 xf = *reinterpret_cast<const float4*>(&Xt[k][4 * tr]);
            float4 wf = *reinterpret_cast<const float4*>(&Wsh[k][4 * tc]);
            float xs[4] = {xf.x, xf.y, xf.z, xf.w};
            float ws[4] = {wf.x, wf.y, wf.z, wf.w};
#pragma unroll
            for (int i = 0; i < 4; ++i)
#pragma unroll
                for (int j = 0; j < 4; ++j)
                    acc[i][j] = fmaf(xs[i], ws[j], acc[i][j]);
        }
    }
    float4* O4 = (float4*)AB;
#pragma unroll
    for (int i = 0; i < 4; ++i) {
        int g = row0 + 4 * tr + i;
        O4[((z * NG + g) * HID + y * 128) / 4 + tc] =
            make_float4(acc[i][0], acc[i][1], acc[i][2], acc[i][3]);
    }
}

// ---------------- pair epilogue ----------------
__global__ __launch_bounds__(256) void k_pair(const float* __restrict__ AB,
                                              const int* __restrict__ ddb,
                                              const int* __restrict__ ecl,
                                              const float* __restrict__ B1,
                                              const float* __restrict__ W2,
                                              const float* __restrict__ B2,
                                              float* __restrict__ out) {
    int p = blockIdx.x * 4 + (threadIdx.x >> 6);
    int lane = threadIdx.x & 63;
    int c = ecl[p];
    int a = ddb[p];
    int b = ddb[NP + p];
    const float4* rA = (const float4*)&AB[((c * 2 + 0) * NG + a) * HID];
    const float4* rB = (const float4*)&AB[((c * 2 + 1) * NG + b) * HID];
    const float4* b1 = (const float4*)&B1[c * HID];
    const float4* w2 = (const float4*)&W2[c * HID];
    float4 va = rA[lane], vb = rB[lane], v1 = b1[lane], v2 = w2[lane];
    float hx = va.x + vb.x + v1.x;
    float hy = va.y + vb.y + v1.y;
    float hz = va.z + vb.z + v1.z;
    float hw = va.w + vb.w + v1.w;
    float s = 0.f;
    s = fmaf(hx > 0.f ? hx : 0.f, v2.x, s);
    s = fmaf(hy > 0.f ? hy : 0.f, v2.y, s);
    s = fmaf(hz > 0.f ? hz : 0.f, v2.z, s);
    s = fmaf(hw > 0.f ? hw : 0.f, v2.w, s);
    for (int o = 32; o; o >>= 1) s += __shfl_down(s, o, 64);
    if (lane == 0) out[p] = s + B2[c];
}

// ---------------- launch ----------------
extern "C" void kernel_launch(void* const* d_in, const int* in_sizes, int n_in,
                              void* d_out, int out_size, void* d_ws, size_t ws_size,
                              hipStream_t stream) {
    const float* x    = (const float*)d_in[0];
    const float* c1w  = (const float*)d_in[1];
    const float* c1b  = (const float*)d_in[2];
    const float* c2w  = (const float*)d_in[3];
    const float* c2b  = (const float*)d_in[4];
    const float* rw1  = (const float*)d_in[5];
    const float* rb1  = (const float*)d_in[6];
    const float* rw2  = (const float*)d_in[7];
    const float* rb2  = (const float*)d_in[8];
    const int*   eidx = (const int*)d_in[9];    // [2, NE]: rows then cols
    const int*   batch= (const int*)d_in[10];
    const int*   ddb  = (const int*)d_in[11];   // [2, NP]
    const int*   ecl  = (const int*)d_in[12];
    float* out = (float*)d_out;

    // ---- workspace layout (floats) ----
    // off(50048) | srows(NE) | dinv(50048) | bufA(NN*128) | bufB(NN*128)
    // transient in bufA pre-gather1: degi, bsums
    // transient in bufB: xs (fp16 NN*64 -> dead after gather1), then H1h (fp16
    //   NN*128, written by gemm1, dead after gather2), then H2 (f32, gemm2 out)
    // transient in srows post-pool: gsum(NG*EMB)
    // transient over bufA post-pool: AB (32*NG*HID)
    int*   off   = (int*)d_ws;
    int*   srows = off + 50048;
    float* dinv  = (float*)(srows + NE);
    float* bufA  = dinv + 50048;
    float* bufB  = bufA + NN * EMB;

    int*   degi  = (int*)bufA;
    int*   bsums = degi + 50048;
    __half* xs   = (__half*)bufB;      // alive only until gather1
    __half* H1h  = (__half*)bufB;      // alive gemm1 -> gather2
    float* gsum  = (float*)srows;      // alive only after pool
    float* AB    = bufA;               // alive only after pool

    const int* erow = eidx;
    const int* ecol = eidx + NE;

    // ---- CSR build ----
    k_zeroi<<<CDIV(NN,256),256,0,stream>>>(degi, NN);
    k_deg<<<CDIV(NE,256),256,0,stream>>>(ecol, degi);
    k_scan1<<<SCAN_BLOCKS,256,0,stream>>>(degi, off, bsums, dinv);
    k_scan2<<<1,256,0,stream>>>(bsums);
    k_scan3<<<SCAN_BLOCKS,256,0,stream>>>(off, bsums);
    k_fill<<<CDIV(NE,256),256,0,stream>>>(erow, ecol, off, srows);

    // ---- layer 1: x'(fp16) = dinv*x ; aggX = gather(x') ; H1'(fp16) = dinv*relu(aggX@W1+b1) ----
    k_scalex<<<CDIV(NN*16,256),256,0,stream>>>(x, dinv, xs);
    k_gath_h<INCH><<<CDIV(NN,4),256,0,stream>>>(off, srows, dinv, xs, bufA);
    gemm32<INCH,true,true,true><<<CDIV(NN,32),256,0,stream>>>(bufA, c1w, c1b, dinv, (float*)H1h, NN);

    // ---- layer 2: aggH = gather(H1') ; H2 = relu(aggH@W2+b2) (f32, into bufB) ----
    k_gath_h<EMB><<<CDIV(NN,4),256,0,stream>>>(off, srows, dinv, H1h, bufA);
    gemm32<EMB,true,false,false><<<CDIV(NN,32),256,0,stream>>>(bufA, c2w, c2b, nullptr, bufB, NN);

    // ---- mean pool over sorted batch (srows/off/dinv dead; gsum aliases srows) ----
    k_pool2<<<NG,128,0,stream>>>(bufB, batch, gsum);

    // ---- regressor: precompute GE @ W1 halves for all 16 lines ----
    dim3 bgrid(NG/32, 2, 2*NCL);
    gemm_bat<<<bgrid,256,0,stream>>>(gsum, rw1, AB);
    k_pair<<<NP/4,256,0,stream>>>(AB, ddb, ecl, rb1, rw2, rb2, out);
}

// Round 8
// 204.175 us; speedup vs baseline: 1.9919x; 1.3255x over previous
//
#include <hip/hip_runtime.h>
#include <hip/hip_fp16.h>

#define NN 50000     // nodes
#define NE 800000    // edges
#define NG 1024      // graphs
#define NP 16384     // pairs
#define NCL 16       // cell lines
#define INCH 64
#define EMB 128
#define HID 256

#define NB 391       // node buckets of 128 (CDIV(NN,128))
#define NCHUNK 400   // edge chunks
#define EPB 2000     // edges per chunk (NE = 400*2000 exactly)

#define CDIV(a,b) (((a)+(b)-1)/(b))

// ---------------- block exclusive scan (NW waves) ----------------
template<int NW>
__device__ __forceinline__ int block_excl_scan(int v, int t, int* incl_out) {
    int lane = t & 63, w = t >> 6;
    int s = v;
#pragma unroll
    for (int d = 1; d < 64; d <<= 1) {
        int u = __shfl_up(s, d, 64);
        if (lane >= d) s += u;
    }
    __shared__ int wsum[NW];
    if (lane == 63) wsum[w] = s;
    __syncthreads();
    int add = 0;
    for (int k = 0; k < w; ++k) add += wsum[k];
    *incl_out = s + add;
    return s + add - v;
}

// ---------------- Pass A: per-chunk bucket histogram ----------------
__global__ __launch_bounds__(256) void k_cnt(const int* __restrict__ cols,
                                             int* __restrict__ cnt) {
    __shared__ int hist[NB];
    int ch = blockIdx.x, t = threadIdx.x;
    for (int b = t; b < NB; b += 256) hist[b] = 0;
    __syncthreads();
    for (int e = ch * EPB + t; e < (ch + 1) * EPB; e += 256)
        atomicAdd(&hist[cols[e] >> 7], 1);
    __syncthreads();
    for (int b = t; b < NB; b += 256) cnt[b * NCHUNK + ch] = hist[b];
}

// ---------------- Pass B1: per-bucket scan over chunks ----------------
__global__ __launch_bounds__(512) void k_bscan(int* __restrict__ cnt,
                                               int* __restrict__ btot) {
    int b = blockIdx.x, t = threadIdx.x;
    int v = (t < NCHUNK) ? cnt[b * NCHUNK + t] : 0;
    int incl;
    int excl = block_excl_scan<8>(v, t, &incl);
    if (t < NCHUNK) cnt[b * NCHUNK + t] = excl;
    if (t == NCHUNK - 1) btot[b] = incl;
}

// ---------------- Pass B2: bucket-base scan ----------------
__global__ __launch_bounds__(512) void k_btot(const int* __restrict__ btot,
                                              int* __restrict__ bbase) {
    int t = threadIdx.x;
    int v = (t < NB) ? btot[t] : 0;
    int incl;
    int excl = block_excl_scan<8>(v, t, &incl);
    if (t < NB) bbase[t] = excl;
    if (t == NB - 1) bbase[NB] = incl;   // = NE
}

// ---------------- Pass C: partition edges into bucket-grouped ebuf ----------------
__global__ __launch_bounds__(256) void k_part(const int* __restrict__ rows,
                                              const int* __restrict__ cols,
                                              const int* __restrict__ cnt,
                                              const int* __restrict__ bbase,
                                              int2* __restrict__ ebuf) {
    __shared__ int cur[NB];
    int ch = blockIdx.x, t = threadIdx.x;
    for (int b = t; b < NB; b += 256) cur[b] = bbase[b] + cnt[b * NCHUNK + ch];
    __syncthreads();
    for (int e = ch * EPB + t; e < (ch + 1) * EPB; e += 256) {
        int c = cols[e], r = rows[e];
        int pos = atomicAdd(&cur[c >> 7], 1);
        ebuf[pos] = make_int2(r, c);
    }
}

// ---------------- Pass D: per-bucket counting sort -> srows/off/dinv + x->fp16 ----------------
__global__ __launch_bounds__(256) void k_bsort(const int2* __restrict__ ebuf,
                                               const int* __restrict__ bbase,
                                               const float* __restrict__ x,
                                               int* __restrict__ off,
                                               float* __restrict__ dinv,
                                               int* __restrict__ srows,
                                               __half* __restrict__ xs) {
    __shared__ int   ldeg[128];
    __shared__ int   lcur[128];
    __shared__ float ldinv[128];
    int b = blockIdx.x, t = threadIdx.x;
    int n0 = b << 7;
    int nloc = min(128, NN - n0);
    int beg = bbase[b], end = bbase[b + 1];
    if (t < 128) ldeg[t] = 0;
    __syncthreads();
    for (int i = beg + t; i < end; i += 256)
        atomicAdd(&ldeg[ebuf[i].y - n0], 1);
    __syncthreads();
    int v = (t < nloc) ? ldeg[t] : 0;
    int incl;
    int excl = block_excl_scan<4>(v, t, &incl);
    if (t < nloc) {
        off[n0 + t]  = beg + excl + v;            // END offset convention
        float d = rsqrtf((float)(v + 1));         // +1 self-loop
        dinv[n0 + t] = d;
        ldinv[t] = d;
        lcur[t] = beg + excl;
    }
    __syncthreads();
    // place edges
    for (int i = beg + t; i < end; i += 256) {
        int2 e = ebuf[i];
        int pos = atomicAdd(&lcur[e.y - n0], 1);
        srows[pos] = e.x;
    }
    // fused: xs[row] = fp16(dinv[row] * x[row]) for this bucket's rows
    const float4* Xx = (const float4*)x;
#pragma unroll
    for (int i = 0; i < 8; ++i) {
        int f4 = t + i * 256;                     // 0..2047
        int rloc = f4 >> 4, kq = f4 & 15;
        if (rloc < nloc) {
            float d = ldinv[rloc];
            float4 vv = Xx[(size_t)(n0 + rloc) * 16 + kq];
            __half2 h[2];
            h[0] = __floats2half2_rn(d * vv.x, d * vv.y);
            h[1] = __floats2half2_rn(d * vv.z, d * vv.w);
            ((float2*)xs)[(size_t)(n0 + rloc) * 16 + kq] = *(float2*)h;
        }
    }
}

// ---------------- gather on pre-scaled fp16 rows ----------------
// SRC' (fp16) already scaled by dinv[row]; DST[c] = dinv[c]*(sum_e SRC'[r] + SRC'[c]).
template<int FEAT>
__global__ __launch_bounds__(256) void k_gath_h(const int* __restrict__ off,
                                                const int* __restrict__ srows,
                                                const float* __restrict__ dinv,
                                                const __half* __restrict__ SRC,
                                                float* __restrict__ DST) {
    constexpr int NC = FEAT / 8;    // 16B chunks per row
    constexpr int PL = NC / 8;      // chunks per lane (1 for 64, 2 for 128)
    int node = blockIdx.x * 4 + (threadIdx.x >> 6);
    int lane = threadIdx.x & 63;
    int slot = lane >> 3, q = lane & 7;
    if (node >= NN) return;
    int beg = node ? off[node - 1] : 0;
    int end = off[node];
    float di = dinv[node];
    const float4* S4 = (const float4*)SRC;

    float acc[PL][8];
#pragma unroll
    for (int i = 0; i < PL; ++i)
#pragma unroll
        for (int j = 0; j < 8; ++j) acc[i][j] = 0.f;

    if (slot == 0) {
#pragma unroll
        for (int i = 0; i < PL; ++i) {
            float4 raw = S4[node * NC + i * 8 + q];
            const __half2* h = (const __half2*)&raw;
#pragma unroll
            for (int j = 0; j < 4; ++j) {
                float2 f = __half22float2(h[j]);
                acc[i][2 * j + 0] = f.x;
                acc[i][2 * j + 1] = f.y;
            }
        }
    }
    for (int e = beg + slot; e < end; e += 8) {
        int r = srows[e];
#pragma unroll
        for (int i = 0; i < PL; ++i) {
            float4 raw = S4[r * NC + i * 8 + q];
            const __half2* h = (const __half2*)&raw;
#pragma unroll
            for (int j = 0; j < 4; ++j) {
                float2 f = __half22float2(h[j]);
                acc[i][2 * j + 0] += f.x;
                acc[i][2 * j + 1] += f.y;
            }
        }
    }
#pragma unroll
    for (int d = 8; d < 64; d <<= 1)
#pragma unroll
        for (int i = 0; i < PL; ++i)
#pragma unroll
            for (int j = 0; j < 8; ++j)
                acc[i][j] += __shfl_xor(acc[i][j], d, 64);

    if (lane < 8) {
        float4* D4 = (float4*)DST;
        constexpr int NV4 = FEAT / 4;
#pragma unroll
        for (int i = 0; i < PL; ++i) {
            float4 o0 = make_float4(di * acc[i][0], di * acc[i][1],
                                    di * acc[i][2], di * acc[i][3]);
            float4 o1 = make_float4(di * acc[i][4], di * acc[i][5],
                                    di * acc[i][6], di * acc[i][7]);
            D4[node * NV4 + (i * 8 + lane) * 2 + 0] = o0;
            D4[node * NV4 + (i * 8 + lane) * 2 + 1] = o1;
        }
    }
}

// ---------------- GEMM: Y[M,128] = X[M,K] @ W[K,128] (+bias,relu[,rowscale][,half out]) ----------------
template<int K, bool EPI, bool RS, bool HOUT>
__global__ __launch_bounds__(256) void gemm32(const float* __restrict__ X,
                                              const float* __restrict__ W,
                                              const float* __restrict__ bias,
                                              const float* __restrict__ rs,
                                              float* __restrict__ Y, int M) {
    __shared__ float Xt[32][36];
    __shared__ float Wsh[32][128];
    const int t  = threadIdx.x;
    const int tr = t >> 5;
    const int tc = t & 31;
    const int row0 = blockIdx.x * 32;
    const int rr = t >> 3, kq = t & 7;

    float acc[4][4];
#pragma unroll
    for (int i = 0; i < 4; ++i)
#pragma unroll
        for (int j = 0; j < 4; ++j) acc[i][j] = 0.f;

    const float4* X4 = (const float4*)X;
    const float4* W4 = (const float4*)W;
    float4* Ws4 = (float4*)&Wsh[0][0];

    for (int k0 = 0; k0 < K; k0 += 32) {
        __syncthreads();
        int gr = row0 + rr;
        float4 xv = (gr < M) ? X4[gr * (K >> 2) + (k0 >> 2) + kq]
                             : make_float4(0.f, 0.f, 0.f, 0.f);
        Xt[4 * kq + 0][rr] = xv.x;
        Xt[4 * kq + 1][rr] = xv.y;
        Xt[4 * kq + 2][rr] = xv.z;
        Xt[4 * kq + 3][rr] = xv.w;
#pragma unroll
        for (int i = t; i < 32 * 32; i += 256)
            Ws4[i] = W4[(k0 + (i >> 5)) * 32 + (i & 31)];
        __syncthreads();
#pragma unroll 4
        for (int k = 0; k < 32; ++k) {
            float4 xf = *reinterpret_cast<const float4*>(&Xt[k][4 * tr]);
            float4 wf = *reinterpret_cast<const float4*>(&Wsh[k][4 * tc]);
            float xs[4] = {xf.x, xf.y, xf.z, xf.w};
            float ws[4] = {wf.x, wf.y, wf.z, wf.w};
#pragma unroll
            for (int i = 0; i < 4; ++i)
#pragma unroll
                for (int j = 0; j < 4; ++j)
                    acc[i][j] = fmaf(xs[i], ws[j], acc[i][j]);
        }
    }
    float4 b = make_float4(0.f, 0.f, 0.f, 0.f);
    if (EPI) b = ((const float4*)bias)[tc];
    float4* Y4 = (float4*)Y;
    __half*  Yh = (__half*)Y;
#pragma unroll
    for (int i = 0; i < 4; ++i) {
        int gr = row0 + 4 * tr + i;
        if (gr < M) {
            float4 o = make_float4(acc[i][0] + b.x, acc[i][1] + b.y,
                                   acc[i][2] + b.z, acc[i][3] + b.w);
            if (EPI) {
                o.x = o.x > 0.f ? o.x : 0.f;
                o.y = o.y > 0.f ? o.y : 0.f;
                o.z = o.z > 0.f ? o.z : 0.f;
                o.w = o.w > 0.f ? o.w : 0.f;
            }
            if (RS) {
                float d = rs[gr];
                o.x *= d; o.y *= d; o.z *= d; o.w *= d;
            }
            if (HOUT) {
                __half2 h[2];
                h[0] = __floats2half2_rn(o.x, o.y);
                h[1] = __floats2half2_rn(o.z, o.w);
                ((float2*)Yh)[gr * 32 + tc] = *(float2*)h;
            } else {
                Y4[gr * 32 + tc] = o;
            }
        }
    }
}

// ---------------- mean pool (gstart search fused) ----------------
__global__ __launch_bounds__(128) void k_pool2(const float* __restrict__ H,
                                               const int* __restrict__ batch,
                                               float* __restrict__ gsum) {
    int g = blockIdx.x;
    __shared__ int se[2];
    if (threadIdx.x < 2) {
        int tgt = g + threadIdx.x;
        int lo = 0, hi = NN;
        while (lo < hi) {
            int m = (lo + hi) >> 1;
            if (batch[m] < tgt) lo = m + 1; else hi = m;
        }
        se[threadIdx.x] = lo;
    }
    __syncthreads();
    int s = se[0], e = se[1];
    int j = threadIdx.x;
    float acc = 0.f;
    for (int i = s; i < e; ++i) acc += H[(long long)i * 128 + j];
    float c = (float)(e - s);
    gsum[g * 128 + j] = acc / fmaxf(c, 1.f);
}

// ---------------- batched GEMM: AB[z][g][t] = GE @ W1-half (128x128 tile, 8x8/thr) ----------------
__global__ __launch_bounds__(256) void gemm_bat(const float* __restrict__ GE,
                                                const float* __restrict__ W1,
                                                float* __restrict__ AB) {
    __shared__ float Xt[32][132];
    __shared__ float Wsh[32][128];
    const int t  = threadIdx.x;
    const int tr = t >> 4;          // 0..15 -> rows 8tr..8tr+7
    const int tc = t & 15;          // 0..15 -> cols 8tc..8tc+7
    const int row0 = blockIdx.x * 128;
    const int y = blockIdx.y;       // col panel (0/1)
    const int z = blockIdx.z;       // c*2 + part

    const float* Wbase = W1 + (z >> 1) * (HID * HID) + (z & 1) * (128 * HID) + y * 128;

    float acc[8][8];
#pragma unroll
    for (int i = 0; i < 8; ++i)
#pragma unroll
        for (int j = 0; j < 8; ++j) acc[i][j] = 0.f;

    const float4* X4 = (const float4*)GE;

    for (int k0 = 0; k0 < 128; k0 += 32) {
        __syncthreads();
#pragma unroll
        for (int i = 0; i < 4; ++i) {
            int f4 = t + i * 256;            // 0..1023
            int row = f4 >> 3, kq = f4 & 7;
            float4 xv = X4[(row0 + row) * 32 + (k0 >> 2) + kq];
            Xt[4 * kq + 0][row] = xv.x;
            Xt[4 * kq + 1][row] = xv.y;
            Xt[4 * kq + 2][row] = xv.z;
            Xt[4 * kq + 3][row] = xv.w;
        }
        const float4* Wc4 = (const float4*)(Wbase + k0 * HID);
#pragma unroll
        for (int i = 0; i < 4; ++i) {
            int f4 = t + i * 256;
            int k = f4 >> 5, c4 = f4 & 31;   // 32 float4s = 128 cols per k
            ((float4*)&Wsh[k][0])[c4] = Wc4[k * 64 + c4];   // row stride HID/4
        }
        __syncthreads();
#pragma unroll 2
        for (int k = 0; k < 32; ++k) {
            float xf[8], wf[8];
            *(float4*)&xf[0] = *(const float4*)&Xt[k][8 * tr];
            *(float4*)&xf[4] = *(const float4*)&Xt[k][8 * tr + 4];
            *(float4*)&wf[0] = *(const float4*)&Wsh[k][8 * tc];
            *(float4*)&wf[4] = *(const float4*)&Wsh[k][8 * tc + 4];
#pragma unroll
            for (int i = 0; i < 8; ++i)
#pragma unroll
                for (int j = 0; j < 8; ++j)
                    acc[i][j] = fmaf(xf[i], wf[j], acc[i][j]);
        }
    }
    float4* O4 = (float4*)AB;
#pragma unroll
    for (int i = 0; i < 8; ++i) {
        int g = row0 + 8 * tr + i;
        size_t base = ((size_t)(z * NG + g) * HID + y * 128 + 8 * tc) >> 2;
        O4[base + 0] = make_float4(acc[i][0], acc[i][1], acc[i][2], acc[i][3]);
        O4[base + 1] = make_float4(acc[i][4], acc[i][5], acc[i][6], acc[i][7]);
    }
}

// ---------------- pair epilogue ----------------
__global__ __launch_bounds__(256) void k_pair(const float* __restrict__ AB,
                                              const int* __restrict__ ddb,
                                              const int* __restrict__ ecl,
                                              const float* __restrict__ B1,
                                              const float* __restrict__ W2,
                                              const float* __restrict__ B2,
                                              float* __restrict__ out) {
    int p = blockIdx.x * 4 + (threadIdx.x >> 6);
    int lane = threadIdx.x & 63;
    int c = ecl[p];
    int a = ddb[p];
    int b = ddb[NP + p];
    const float4* rA = (const float4*)&AB[((c * 2 + 0) * NG + a) * HID];
    const float4* rB = (const float4*)&AB[((c * 2 + 1) * NG + b) * HID];
    const float4* b1 = (const float4*)&B1[c * HID];
    const float4* w2 = (const float4*)&W2[c * HID];
    float4 va = rA[lane], vb = rB[lane], v1 = b1[lane], v2 = w2[lane];
    float hx = va.x + vb.x + v1.x;
    float hy = va.y + vb.y + v1.y;
    float hz = va.z + vb.z + v1.z;
    float hw = va.w + vb.w + v1.w;
    float s = 0.f;
    s = fmaf(hx > 0.f ? hx : 0.f, v2.x, s);
    s = fmaf(hy > 0.f ? hy : 0.f, v2.y, s);
    s = fmaf(hz > 0.f ? hz : 0.f, v2.z, s);
    s = fmaf(hw > 0.f ? hw : 0.f, v2.w, s);
    for (int o = 32; o; o >>= 1) s += __shfl_down(s, o, 64);
    if (lane == 0) out[p] = s + B2[c];
}

// ---------------- launch ----------------
extern "C" void kernel_launch(void* const* d_in, const int* in_sizes, int n_in,
                              void* d_out, int out_size, void* d_ws, size_t ws_size,
                              hipStream_t stream) {
    const float* x    = (const float*)d_in[0];
    const float* c1w  = (const float*)d_in[1];
    const float* c1b  = (const float*)d_in[2];
    const float* c2w  = (const float*)d_in[3];
    const float* c2b  = (const float*)d_in[4];
    const float* rw1  = (const float*)d_in[5];
    const float* rb1  = (const float*)d_in[6];
    const float* rw2  = (const float*)d_in[7];
    const float* rb2  = (const float*)d_in[8];
    const int*   eidx = (const int*)d_in[9];    // [2, NE]: rows then cols
    const int*   batch= (const int*)d_in[10];
    const int*   ddb  = (const int*)d_in[11];   // [2, NP]
    const int*   ecl  = (const int*)d_in[12];
    float* out = (float*)d_out;

    // ---- workspace layout (floats) ----
    // off(50048) | srows(NE) | dinv(50048) | bufA(NN*128) | bufB(NN*128)
    // aliases:
    //   ebuf (int2, NE)       -> bufA[0 .. 1.6M floats)      (passes C..D)
    //   cnt/btot/bbase (ints) -> bufB[1.70M .. 1.86M floats) (passes A..D)
    //   xs  (fp16 NN*64)      -> bufB[0 .. 1.6M floats)      (D .. gather1)
    //   H1h (fp16 NN*128)     -> bufB[0 .. 3.2M floats)      (gemm1 .. gather2)
    //   H2  (f32 NN*128)      -> bufB                        (gemm2 .. pool)
    //   gsum                  -> srows region                (post gather2)
    //   AB (32*NG*HID f32)    -> bufA (+spills into bufB)    (post pool)
    int*   off   = (int*)d_ws;
    int*   srows = off + 50048;
    float* dinv  = (float*)(srows + NE);
    float* bufA  = dinv + 50048;
    float* bufB  = bufA + NN * EMB;

    int2*  ebuf  = (int2*)bufA;
    int*   cnt   = (int*)(bufB + 1700000);
    int*   btot  = cnt + NB * NCHUNK;          // 156400
    int*   bbase = btot + 512;
    __half* xs   = (__half*)bufB;
    __half* H1h  = (__half*)bufB;
    float* gsum  = (float*)srows;
    float* AB    = bufA;

    const int* erow = eidx;
    const int* ecol = eidx + NE;

    // ---- CSR build (bucketed, LDS-atomic only) + fused x->fp16 prescale ----
    k_cnt  <<<NCHUNK, 256, 0, stream>>>(ecol, cnt);
    k_bscan<<<NB,     512, 0, stream>>>(cnt, btot);
    k_btot <<<1,      512, 0, stream>>>(btot, bbase);
    k_part <<<NCHUNK, 256, 0, stream>>>(erow, ecol, cnt, bbase, ebuf);
    k_bsort<<<NB,     256, 0, stream>>>(ebuf, bbase, x, off, dinv, srows, xs);

    // ---- layer 1: aggX = gather(xs) ; H1'(fp16) = dinv*relu(aggX@W1+b1) ----
    k_gath_h<INCH><<<CDIV(NN,4),256,0,stream>>>(off, srows, dinv, xs, bufA);
    gemm32<INCH,true,true,true><<<CDIV(NN,32),256,0,stream>>>(bufA, c1w, c1b, dinv, (float*)H1h, NN);

    // ---- layer 2: aggH = gather(H1') ; H2 = relu(aggH@W2+b2) ----
    k_gath_h<EMB><<<CDIV(NN,4),256,0,stream>>>(off, srows, dinv, H1h, bufA);
    gemm32<EMB,true,false,false><<<CDIV(NN,32),256,0,stream>>>(bufA, c2w, c2b, nullptr, bufB, NN);

    // ---- mean pool over sorted batch ----
    k_pool2<<<NG,128,0,stream>>>(bufB, batch, gsum);

    // ---- regressor: AB = GE @ W1 halves for all 16 lines, then pair epilogue ----
    dim3 bgrid(NG/128, 2, 2*NCL);
    gemm_bat<<<bgrid,256,0,stream>>>(gsum, rw1, AB);
    k_pair<<<NP/4,256,0,stream>>>(AB, ddb, ecl, rb1, rw2, rb2, out);
}